// Round 4
// baseline (597.901 us; speedup 1.0000x reference)
//
#include <hip/hip_runtime.h>
#include <cstdint>
#include <cstddef>

// Problem constants (match reference setup_inputs)
#define Bb   256
#define Tt   250
#define DIN  700
#define Hh   128
#define DOUT 20

// ---------------------------------------------------------------------------
// Phase 1: EXACT R0 gemm (217 us, VGPR 92). Do not touch.
// ---------------------------------------------------------------------------
constexpr int BM  = 128;
constexpr int BK  = 20;
constexpr int BN  = 128;
constexpr int BMP = BM + 4;

__device__ __forceinline__ int bswz(int g) { return g ^ (g >> 3); }

__global__ __launch_bounds__(256, 2) void gemm_h1(const float* __restrict__ x,
                                                  const float* __restrict__ W1,
                                                  const float* __restrict__ b1,
                                                  float* __restrict__ H1) {
    __shared__ float Ast[BK][BMP];
    __shared__ float Bs[BK][BN];

    const int tid = threadIdx.x;
    const int tx  = tid & 15;
    const int ty  = tid >> 4;
    const int m0  = blockIdx.x * BM;

    const int c0 = bswz(tx * 2) * 4;
    const int c1 = bswz(tx * 2 + 1) * 4;

    float acc[8][8];
#pragma unroll
    for (int r = 0; r < 8; ++r)
#pragma unroll
        for (int c = 0; c < 8; ++c) acc[r][c] = 0.f;

    for (int k0 = 0; k0 < DIN; k0 += BK) {
#pragma unroll
        for (int idx = tid; idx < 640; idx += 256) {
            int row = idx / 5;
            int kq  = (idx - row * 5) * 4;
            const float4 v =
                *(const float4*)&x[(size_t)(m0 + row) * DIN + (k0 + kq)];
            Ast[kq + 0][row] = v.x;
            Ast[kq + 1][row] = v.y;
            Ast[kq + 2][row] = v.z;
            Ast[kq + 3][row] = v.w;
        }
#pragma unroll
        for (int idx = tid; idx < 640; idx += 256) {
            int kr = idx >> 5;
            int g  = idx & 31;
            *(float4*)&Bs[kr][bswz(g) * 4] =
                *(const float4*)&W1[(size_t)(k0 + kr) * BN + g * 4];
        }
        __syncthreads();

#pragma unroll
        for (int kk = 0; kk < BK; ++kk) {
            float a[8], bv[8];
            *(float4*)&a[0]  = *(const float4*)&Ast[kk][ty * 8];
            *(float4*)&a[4]  = *(const float4*)&Ast[kk][ty * 8 + 4];
            *(float4*)&bv[0] = *(const float4*)&Bs[kk][c0];
            *(float4*)&bv[4] = *(const float4*)&Bs[kk][c1];
#pragma unroll
            for (int r = 0; r < 8; ++r)
#pragma unroll
                for (int c = 0; c < 8; ++c)
                    acc[r][c] = fmaf(a[r], bv[c], acc[r][c]);
        }
        __syncthreads();
    }

    float bb[8];
#pragma unroll
    for (int c = 0; c < 8; ++c) bb[c] = b1[tx * 8 + c];

#pragma unroll
    for (int r = 0; r < 8; ++r) {
        size_t row = (size_t)(m0 + ty * 8 + r);
        float4 o0, o1;
        o0.x = acc[r][0] + bb[0]; o0.y = acc[r][1] + bb[1];
        o0.z = acc[r][2] + bb[2]; o0.w = acc[r][3] + bb[3];
        o1.x = acc[r][4] + bb[4]; o1.y = acc[r][5] + bb[5];
        o1.z = acc[r][6] + bb[6]; o1.w = acc[r][7] + bb[7];
        *(float4*)&H1[row * Hh + tx * 8]     = o0;
        *(float4*)&H1[row * Hh + tx * 8 + 4] = o1;
    }
}

// ---------------------------------------------------------------------------
// Shared phase-2 machinery
// ---------------------------------------------------------------------------
#define WAITV(N)                                                       \
    asm volatile("s_waitcnt vmcnt(" #N ")" ::: "memory");              \
    __builtin_amdgcn_sched_barrier(0)

__device__ __forceinline__ void gll16(const void* g, void* l) {
    __builtin_amdgcn_global_load_lds(
        (const __attribute__((address_space(1))) uint32_t*)g,
        (__attribute__((address_space(3))) uint32_t*)l, 16, 0, 0);
}

__device__ __forceinline__ void issue_chunk(const char* hg, char* ringb,
                                            int c, int n) {
    const char* g = hg + (size_t)c * 4096;
    char* l = ringb + (c & 3) * 4096;
    for (int i = 0; i < n; ++i) gll16(g + (size_t)i * 1024, l + i * 1024);
}

#define EXTR(K)                                                        \
    if (mlo) { K = (int)__ffsll(mlo) - 1; mlo &= mlo - 1ull; }         \
    else     { K = 64 + (int)__ffsll(mhi) - 1; mhi &= mhi - 1ull; }
#define EXTR2(K)                                                       \
    if (mlo)      { K = (int)__ffsll(mlo) - 1; mlo &= mlo - 1ull; }    \
    else if (mhi) { K = 64 + (int)__ffsll(mhi) - 1; mhi &= mhi - 1ull; }

// ---------------------------------------------------------------------------
// ABLATION B: pure h1-stream (ring + refills + accumulate). 3 passes.
// Measures the delivery machinery alone. Output is garbage; overwritten by
// the real recurrent (final dispatch), so correctness is unaffected.
// ---------------------------------------------------------------------------
__global__ __launch_bounds__(64) void rec_stream(const float* __restrict__ H1,
                                                 float* __restrict__ out) {
    __shared__ float ring[32 * Hh];
    const int lane = threadIdx.x;
    const int b    = blockIdx.x;
    const char* hg = (const char*)(H1 + (size_t)b * Tt * Hh) + lane * 16;
    char* ringb = (char*)ring;
    float accx = 0.f, accy = 0.f;

#pragma unroll 1
    for (int pass = 0; pass < 3; ++pass) {
        issue_chunk(hg, ringb, 0, 4);
        issue_chunk(hg, ringb, 1, 4);
        issue_chunk(hg, ringb, 2, 4);
        WAITV(4);
        float h1xs[4], h1ys[4];
#pragma unroll
        for (int j = 0; j < 4; ++j) {
            h1xs[j] = ring[(j << 7) + lane];
            h1ys[j] = ring[(j << 7) + lane + 64];
        }
#define BSTEP(T, J)                                                    \
        {                                                              \
            accx += h1xs[J]; accy += h1ys[J];                          \
            int tp = (T) + 4; tp = (tp < Tt) ? tp : (Tt - 1);          \
            const float* rp_ = &ring[(tp & 31) << 7];                  \
            h1xs[J] = rp_[lane];                                       \
            h1ys[J] = rp_[lane + 64];                                  \
        }
#pragma unroll 1
        for (int c = 0; c < 31; ++c) {
            if (c <= 27)      issue_chunk(hg, ringb, c + 3, 4);
            else if (c == 28) issue_chunk(hg, ringb, 31, 1);
            if (c <= 27) { WAITV(8); } else { WAITV(0); }
            const int t0 = c << 3;
#pragma unroll 1
            for (int g = 0; g < 2; ++g) {
                const int t = t0 + (g << 2);
                BSTEP(t + 0, 0) BSTEP(t + 1, 1)
                BSTEP(t + 2, 2) BSTEP(t + 3, 3)
            }
        }
        WAITV(0);
        BSTEP(248, 0) BSTEP(249, 1)
#undef BSTEP
    }
    out[b * DOUT + (lane % DOUT)] = accx + accy;   // garbage; overwritten
}

// ---------------------------------------------------------------------------
// ABLATION A: full skeleton (stream + LIF chains + ballots + branch
// structure), gather MEMORY OPS stripped. Ballots kept live via asm sinks
// inside the original branches (rule: ablation-via-skip DCEs upstream ops).
// 3 passes. Output garbage; overwritten by the real recurrent.
// ---------------------------------------------------------------------------
__global__ __launch_bounds__(64) void rec_skel(
    const float* __restrict__ H1, const float* __restrict__ rcb1,
    const float* __restrict__ b2, const float* __restrict__ rcb2,
    float* __restrict__ out) {

    __shared__ float ring[32 * Hh];
    const int lane = threadIdx.x;
    const int b    = blockIdx.x;

    const float rcb1x = rcb1[lane], rcb1y = rcb1[lane + 64];
    const float bb2x  = b2[lane]      + rcb2[lane];
    const float bb2y  = b2[lane + 64] + rcb2[lane + 64];
    const char* hg = (const char*)(H1 + (size_t)b * Tt * Hh) + lane * 16;
    char* ringb = (char*)ring;

    float v1x = 0.f, v1y = 0.f, v2x = 0.f, v2y = 0.f;
    float cntx = 0.f, cnty = 0.f;

#pragma unroll 1
    for (int pass = 0; pass < 3; ++pass) {
        issue_chunk(hg, ringb, 0, 4);
        issue_chunk(hg, ringb, 1, 4);
        issue_chunk(hg, ringb, 2, 4);
        WAITV(4);
        float h1xs[4], h1ys[4];
#pragma unroll
        for (int j = 0; j < 4; ++j) {
            h1xs[j] = ring[(j << 7) + lane];
            h1ys[j] = ring[(j << 7) + lane + 64];
        }
#define ASTEP(T, J)                                                           \
        {                                                                     \
            const float u1xv = h1xs[J] + rcb1x;                               \
            const float u1yv = h1ys[J] + rcb1y;                               \
            int tp = (T) + 4; tp = (tp < Tt) ? tp : (Tt - 1);                 \
            const float* rp_ = &ring[(tp & 31) << 7];                         \
            h1xs[J] = rp_[lane];                                              \
            h1ys[J] = rp_[lane + 64];                                         \
            v1x = v1x + (u1xv - v1x) * 0.5f;                                  \
            v1y = v1y + (u1yv - v1y) * 0.5f;                                  \
            const bool s1x = (v1x >= 1.0f);                                   \
            const bool s1y = (v1y >= 1.0f);                                   \
            if (s1x) v1x = 0.f;                                               \
            if (s1y) v1y = 0.f;                                               \
            const unsigned long long a0 = __ballot((int)s1x);                 \
            const unsigned long long a1 = __ballot((int)s1y);                 \
            if (a0 | a1) { asm volatile("" :: "s"(a0), "s"(a1)); }            \
            const float u2xv = bb2x;                                          \
            const float u2yv = bb2y;                                          \
            v2x = v2x + (u2xv - v2x) * 0.5f;                                  \
            v2y = v2y + (u2yv - v2y) * 0.5f;                                  \
            const bool s2x = (v2x >= 1.0f);                                   \
            const bool s2y = (v2y >= 1.0f);                                   \
            if (s2x) v2x = 0.f;                                               \
            if (s2y) v2y = 0.f;                                               \
            cntx += s2x ? 1.f : 0.f;                                          \
            cnty += s2y ? 1.f : 0.f;                                          \
            const unsigned long long c0m = __ballot((int)s2x);                \
            const unsigned long long c1m = __ballot((int)s2y);                \
            if (c0m | c1m) { asm volatile("" :: "s"(c0m), "s"(c1m)); }        \
        }
#pragma unroll 1
        for (int c = 0; c < 31; ++c) {
            if (c <= 27)      issue_chunk(hg, ringb, c + 3, 4);
            else if (c == 28) issue_chunk(hg, ringb, 31, 1);
            if (c <= 27) { WAITV(8); } else { WAITV(0); }
            const int t0 = c << 3;
#pragma unroll 1
            for (int g = 0; g < 2; ++g) {
                const int t = t0 + (g << 2);
                ASTEP(t + 0, 0) ASTEP(t + 1, 1)
                ASTEP(t + 2, 2) ASTEP(t + 3, 3)
            }
        }
        WAITV(0);
        ASTEP(248, 0) ASTEP(249, 1)
#undef ASTEP
    }
    out[b * DOUT + (lane % DOUT)] = cntx + cnty;   // garbage; overwritten
}

// ---------------------------------------------------------------------------
// Phase 2, REAL: EXACT R3 recurrent (passed, absmax 0.0). Final dispatch —
// unconditionally rewrites all of d_out, so ablation garbage is erased.
// ---------------------------------------------------------------------------
__global__ __launch_bounds__(64) void recurrent(
    const float* __restrict__ H1,   const float* __restrict__ rcW1,
    const float* __restrict__ rcb1, const float* __restrict__ W2,
    const float* __restrict__ b2,   const float* __restrict__ rcW2,
    const float* __restrict__ rcb2, const float* __restrict__ W3,
    const float* __restrict__ b3,   float* __restrict__ out) {

    __shared__ float W2ls[Hh * Hh];    // 64 KB
    __shared__ float rcW1ls[Hh * Hh];  // 64 KB
    __shared__ float ring[32 * Hh];    // 16 KB

    const int lane = threadIdx.x;
    const int b    = blockIdx.x;

    const float rcb1x = rcb1[lane], rcb1y = rcb1[lane + 64];
    const float bb2x  = b2[lane]      + rcb2[lane];
    const float bb2y  = b2[lane + 64] + rcb2[lane + 64];
    const float* __restrict__ h1p = H1 + (size_t)b * Tt * Hh;

    {
        const char* g2 = (const char*)W2 + lane * 16;
        const char* g1 = (const char*)rcW1 + lane * 16;
        char* l2 = (char*)W2ls;
        char* l1 = (char*)rcW1ls;
#pragma unroll 1
        for (int i = 0; i < 64; ++i) gll16(g2 + (size_t)i * 1024, l2 + i * 1024);
#pragma unroll 1
        for (int i = 0; i < 64; ++i) gll16(g1 + (size_t)i * 1024, l1 + i * 1024);
    }
    const char* hg = (const char*)h1p + lane * 16;
    char* ringb = (char*)ring;
    issue_chunk(hg, ringb, 0, 4);
    issue_chunk(hg, ringb, 1, 4);
    issue_chunk(hg, ringb, 2, 4);
    WAITV(4);

    float v1x = 0.f, v1y = 0.f, v2x = 0.f, v2y = 0.f;
    float cntx = 0.f, cnty = 0.f;
    float u1gx = 0.f, u1gy = 0.f;
    float l0x = 0.f, l0y = 0.f, l1x = 0.f, l1y = 0.f, l2x = 0.f, l2y = 0.f;
    bool  f0 = false, f1 = false, f2 = false;

    float h1xs[4], h1ys[4];
#pragma unroll
    for (int j = 0; j < 4; ++j) {
        h1xs[j] = ring[(j << 7) + lane];
        h1ys[j] = ring[(j << 7) + lane + 64];
    }

#define STEP(T, J)                                                            \
    {                                                                         \
        const int t_ = (T);                                                   \
        const float u1xv = h1xs[J] + rcb1x + u1gx;                            \
        const float u1yv = h1ys[J] + rcb1y + u1gy;                            \
        int tp = t_ + 4; tp = (tp < Tt) ? tp : (Tt - 1);                      \
        const float* rp_ = &ring[(tp & 31) << 7];                             \
        h1xs[J] = rp_[lane];                                                  \
        h1ys[J] = rp_[lane + 64];                                             \
        v1x = v1x + (u1xv - v1x) * 0.5f;                                      \
        v1y = v1y + (u1yv - v1y) * 0.5f;                                      \
        const bool s1x = (v1x >= 1.0f);                                       \
        const bool s1y = (v1y >= 1.0f);                                       \
        if (s1x) v1x = 0.f;                                                   \
        if (s1y) v1y = 0.f;                                                   \
        const unsigned long long a0 = __ballot((int)s1x);                     \
        const unsigned long long a1 = __ballot((int)s1y);                     \
        float uW2x = 0.f, uW2y = 0.f, g1x = 0.f, g1y = 0.f;                   \
        if (a0 | a1) {                                                        \
            unsigned long long mlo = a0, mhi = a1;                            \
            while (mlo | mhi) {                                               \
                int k0; int k1 = -1; int k2 = -1; int k3 = -1;                \
                EXTR(k0) EXTR2(k1) EXTR2(k2) EXTR2(k3)                        \
                const int i0 = k0 << 7;                                       \
                const int i1 = (k1 >= 0 ? k1 : k0) << 7;                      \
                const int i2 = (k2 >= 0 ? k2 : k0) << 7;                      \
                const int i3 = (k3 >= 0 ? k3 : k0) << 7;                      \
                const float w0x = W2ls[i0 + lane],   w0y = W2ls[i0 + 64 + lane];   \
                const float r0x = rcW1ls[i0 + lane], r0y = rcW1ls[i0 + 64 + lane]; \
                const float w1x = W2ls[i1 + lane],   w1y = W2ls[i1 + 64 + lane];   \
                const float r1x = rcW1ls[i1 + lane], r1y = rcW1ls[i1 + 64 + lane]; \
                const float w2x = W2ls[i2 + lane],   w2y = W2ls[i2 + 64 + lane];   \
                const float r2x = rcW1ls[i2 + lane], r2y = rcW1ls[i2 + 64 + lane]; \
                const float w3x = W2ls[i3 + lane],   w3y = W2ls[i3 + 64 + lane];   \
                const float r3x = rcW1ls[i3 + lane], r3y = rcW1ls[i3 + 64 + lane]; \
                uW2x += w0x; uW2y += w0y; g1x += r0x; g1y += r0y;             \
                if (k1 >= 0) { uW2x += w1x; uW2y += w1y; g1x += r1x; g1y += r1y; } \
                if (k2 >= 0) { uW2x += w2x; uW2y += w2y; g1x += r2x; g1y += r2y; } \
                if (k3 >= 0) { uW2x += w3x; uW2y += w3y; g1x += r3x; g1y += r3y; } \
            }                                                                 \
        }                                                                     \
        u1gx = g1x; u1gy = g1y;                                               \
        const float u2gx =                                                    \
            ((f0 ? l0x : 0.f) + (f1 ? l1x : 0.f)) + (f2 ? l2x : 0.f);         \
        const float u2gy =                                                    \
            ((f0 ? l0y : 0.f) + (f1 ? l1y : 0.f)) + (f2 ? l2y : 0.f);         \
        const float u2xv = bb2x + uW2x + u2gx;                                \
        const float u2yv = bb2y + uW2y + u2gy;                                \
        v2x = v2x + (u2xv - v2x) * 0.5f;                                      \
        v2y = v2y + (u2yv - v2y) * 0.5f;                                      \
        const bool s2x = (v2x >= 1.0f);                                       \
        const bool s2y = (v2y >= 1.0f);                                       \
        if (s2x) v2x = 0.f;                                                   \
        if (s2y) v2y = 0.f;                                                   \
        cntx += s2x ? 1.f : 0.f;                                              \
        cnty += s2y ? 1.f : 0.f;                                              \
        const unsigned long long c0m = __ballot((int)s2x);                    \
        const unsigned long long c1m = __ballot((int)s2y);                    \
        f0 = false; f1 = false; f2 = false;                                   \
        if (c0m | c1m) {                                                      \
            unsigned long long mlo = c0m, mhi = c1m;                          \
            const int n2 = __popcll(c0m) + __popcll(c1m);                     \
            if (n2 <= 3) {                                                    \
                int k0; int k1 = -1; int k2 = -1;                             \
                EXTR(k0) EXTR2(k1) EXTR2(k2)                                  \
                const float* p0 = rcW2 + ((size_t)k0 << 7);                   \
                const float* p1 = rcW2 + ((size_t)(k1 >= 0 ? k1 : k0) << 7);  \
                const float* p2 = rcW2 + ((size_t)(k2 >= 0 ? k2 : k0) << 7);  \
                l0x = p0[lane]; l0y = p0[lane + 64];                          \
                l1x = p1[lane]; l1y = p1[lane + 64];                          \
                l2x = p2[lane]; l2y = p2[lane + 64];                          \
                f0 = true; f1 = (k1 >= 0); f2 = (k2 >= 0);                    \
            } else {                                                          \
                float sx = 0.f, sy = 0.f;                                     \
                while (mlo | mhi) {                                           \
                    int kk; EXTR(kk)                                          \
                    const float* pr = rcW2 + ((size_t)kk << 7);               \
                    sx += pr[lane]; sy += pr[lane + 64];                      \
                }                                                             \
                l0x = sx; l0y = sy;                                           \
                l1x = 0.f; l1y = 0.f; l2x = 0.f; l2y = 0.f;                   \
                f0 = true;                                                    \
            }                                                                 \
        }                                                                     \
    }

#pragma unroll 1
    for (int c = 0; c < 31; ++c) {
        if (c <= 27)      issue_chunk(hg, ringb, c + 3, 4);
        else if (c == 28) issue_chunk(hg, ringb, 31, 1);
        if (c <= 27) { WAITV(8); } else { WAITV(0); }
        const int t0 = c << 3;
#pragma unroll 1
        for (int g = 0; g < 2; ++g) {
            const int t = t0 + (g << 2);
            STEP(t + 0, 0)
            STEP(t + 1, 1)
            STEP(t + 2, 2)
            STEP(t + 3, 3)
        }
    }
    WAITV(0);
    STEP(248, 0)
    STEP(249, 1)
#undef STEP

    ring[lane]      = cntx;
    ring[lane + 64] = cnty;
    __syncthreads();
    if (lane < DOUT) {
        float o = (float)Tt * b3[lane];
#pragma unroll 8
        for (int k = 0; k < Hh; ++k) o += ring[k] * W3[k * DOUT + lane];
        out[b * DOUT + lane] = o;
    }
}

// ---------------------------------------------------------------------------
extern "C" void kernel_launch(void* const* d_in, const int* in_sizes, int n_in,
                              void* d_out, int out_size, void* d_ws, size_t ws_size,
                              hipStream_t stream) {
    const float* x    = (const float*)d_in[0];
    const float* W1   = (const float*)d_in[1];
    const float* b1   = (const float*)d_in[2];
    const float* rcW1 = (const float*)d_in[3];
    const float* rcb1 = (const float*)d_in[4];
    const float* W2   = (const float*)d_in[5];
    const float* b2   = (const float*)d_in[6];
    const float* rcW2 = (const float*)d_in[7];
    const float* rcb2 = (const float*)d_in[8];
    const float* W3   = (const float*)d_in[9];
    const float* b3   = (const float*)d_in[10];

    float* out = (float*)d_out;
    float* H1  = (float*)d_ws;   // 64000 x 128 f32 = 32.77 MB

    gemm_h1<<<(Bb * Tt) / BM, 256, 0, stream>>>(x, W1, b1, H1);
    // Diagnostic ablations (outputs are garbage, fully overwritten by the
    // real recurrent below — absmax unaffected):
    rec_stream<<<Bb, 64, 0, stream>>>(H1, out);
    rec_skel<<<Bb, 64, 0, stream>>>(H1, rcb1, b2, rcb2, out);
    // Real pass (exact R3 kernel):
    recurrent<<<Bb, 64, 0, stream>>>(H1, rcW1, rcb1, W2, b2, rcW2, rcb2, W3,
                                     b3, out);
}